// Round 8
// baseline (157.967 us; speedup 1.0000x reference)
//
#include <hip/hip_runtime.h>

// Problem constants (match reference)
constexpr int B        = 65536;
constexpr int N_SPARSE = 20;
constexpr int N_VARLEN = 3;
constexpr int SEQ_LEN  = 50;
constexpr int VOCAB    = 100000;
constexpr int N_DENSE  = 13;
constexpr int VAR_TOT  = N_VARLEN * SEQ_LEN;  // 150

// LDS slicing of the varlen tables (fp16): 10 passes x 10000-entry slices.
constexpr int SLICE = 10000;
constexpr int NPASS = VOCAB / SLICE;          // 10
constexpr int LROW  = SLICE + 2;              // +sentinel (2 halves, keeps rows dword-even)

typedef int   v4i __attribute__((ext_vector_type(4)));
typedef float v2f __attribute__((ext_vector_type(2)));

// ---------- Kernel 1: convert varlen tables fp32 -> fp16 into d_ws ----------
__global__ __launch_bounds__(512) void convert_kernel(
    const float* __restrict__ vt, unsigned int* __restrict__ vt16)
{
    const int i = blockIdx.x * 512 + threadIdx.x;       // one u32 (2 halves) per thread
    if (i >= (N_VARLEN * VOCAB) / 2) return;
    const v2f f = ((const v2f*)vt)[i];
    const unsigned short lo = __builtin_bit_cast(unsigned short, (_Float16)f.x);
    const unsigned short hi = __builtin_bit_cast(unsigned short, (_Float16)f.y);
    vt16[i] = ((unsigned int)hi << 16) | lo;
}

// ---------- Kernel 2: main ----------
// 512 blocks x 1024 threads. 16 lanes own one row PAIR (rows 2g,2g+1); the
// pair's 300 varlen ids live in 20 VGPRs for the whole kernel (NO re-reads).
// R6 post-mortem: global divergent-gather service rate is pinned at ~0.31
// lanes/cyc/CU — so we REMOVE 88% of global gathers by resolving varlen ids
// against LDS-staged fp16 table slices (10 passes x 60 KB).
// Out-of-slice ids: unsigned wrap + min-clamp -> sentinel half = 0.
// id==0 mask: slice-0 entry 0 zeroed during staging (reference masks id==0).
// Row routing + slot validity folded into one +-1/0 weight: two fmas
// accumulate (acc0-acc1) and (acc0+acc1).
__global__ __launch_bounds__(1024) void logit_kernel(
    const int*   __restrict__ sparse_ids,          // [B, 20]
    const int*   __restrict__ varlen_ids,          // [B, 3, 50]
    const float* __restrict__ dense_x,             // [B, 13]
    const float* __restrict__ sparse_tables,       // [20, VOCAB]
    const float* __restrict__ dense_w,             // [13]
    const unsigned int* __restrict__ vt16,         // [3][VOCAB] halves, packed u32
    float*       __restrict__ out)                 // [B]
{
    __shared__ unsigned int ldsw[N_VARLEN * (LROW / 2)];     // 60012 B
    const unsigned short* lds16 = (const unsigned short*)ldsw;

    const int tidb = threadIdx.x;
    const int gtid = blockIdx.x * 1024 + tidb;
    const int g    = gtid >> 4;     // row-pair index, 0 .. B/2-1
    const int t    = gtid & 15;     // lane within pair-group

    // ---- load all ids / dense (nt: pure streams) ----
    const v4i* vptr = (const v4i*)varlen_ids + (long)g * 75;
    v4i vid[5];
    #pragma unroll
    for (int k = 0; k < 4; ++k)
        vid[k] = __builtin_nontemporal_load(vptr + (t + 16 * k));
    vid[4] = __builtin_nontemporal_load(vptr + (t > 10 ? 74 : t + 64));
    const v4i sid = __builtin_nontemporal_load((const v4i*)sparse_ids + (long)g * 10 + (t > 9 ? 9 : t));
    const v2f dx  = __builtin_nontemporal_load((const v2f*)dense_x    + (long)g * 13 + (t > 12 ? 12 : t));

    // ---- issue sparse gathers NOW (global); consume after the pass loop ----
    float sval[4];
    {
        const int c = (t > 9) ? 9 : t;
        #pragma unroll
        for (int j = 0; j < 4; ++j) {
            const int s = 4 * c + j;
            const int f = (s >= N_SPARSE) ? (s - N_SPARSE) : s;
            sval[j] = sparse_tables[f * VOCAB + sid[j]];
        }
    }

    // ---- per-slot invariants: LDS element base (table v) + sign weight ----
    int   vbase[20];
    float wsgn[20];
    #pragma unroll
    for (int k = 0; k < 5; ++k) {
        const int c = (k == 4) ? (t + 64) : (t + 16 * k);
        #pragma unroll
        for (int j = 0; j < 4; ++j) {
            const int s   = 4 * c + j;                 // pair-position
            const bool ok = (s < 2 * VAR_TOT);
            const bool r1 = (s >= VAR_TOT);
            int p = r1 ? (s - VAR_TOT) : s;
            p = (p > VAR_TOT - 1) ? (VAR_TOT - 1) : p;
            const int v = (p >= 100) ? 2 : (p >= 50 ? 1 : 0);
            vbase[4 * k + j] = v * LROW;
            wsgn[4 * k + j]  = ok ? (r1 ? -1.f : 1.f) : 0.f;
        }
    }

    float accS = 0.f, accD = 0.f;   // acc0+acc1, acc0-acc1

    // ---- slice passes over the fp16 varlen tables ----
    for (int p = 0; p < NPASS; ++p) {
        __syncthreads();            // WAR: previous pass's readers done
        // stage slice p: 3 rows x 5000 dwords
        #pragma unroll
        for (int v = 0; v < 3; ++v) {
            const unsigned int* src = vt16 + v * (VOCAB / 2) + p * (SLICE / 2);
            for (int k = tidb; k < SLICE / 2; k += 1024) {
                unsigned int w = src[k];                     // cached: 600 KB, L2-resident
                if (p == 0 && k == 0) w &= 0xffff0000u;      // zero entry id==0
                ldsw[v * (LROW / 2) + k] = w;
            }
        }
        if (tidb < 3) ldsw[tidb * (LROW / 2) + SLICE / 2] = 0;   // sentinel = 0
        __syncthreads();

        const int lo = p * SLICE;
        #pragma unroll
        for (int k = 0; k < 5; ++k) {
            #pragma unroll
            for (int j = 0; j < 4; ++j) {
                const int slot = 4 * k + j;
                unsigned int off = (unsigned int)(vid[k][j] - lo);   // wraps if below
                off = (off > (unsigned)SLICE) ? (unsigned)SLICE : off; // clamp -> sentinel
                const unsigned short raw = lds16[vbase[slot] + (int)off];
                const float val = (float)__builtin_bit_cast(_Float16, raw);
                accD += val * wsgn[slot];
                accS += val * __builtin_fabsf(wsgn[slot]);
            }
        }
    }

    float acc0 = 0.5f * (accS + accD);
    float acc1 = 0.5f * (accS - accD);

    // ---- consume sparse gathers ----
    {
        const int c   = (t > 9) ? 9 : t;
        const bool ok = (t < 10);
        #pragma unroll
        for (int j = 0; j < 4; ++j) {
            const int s   = 4 * c + j;
            const bool r1 = (s >= N_SPARSE);
            const float m = ok ? sval[j] : 0.f;
            acc0 += r1 ? 0.f : m;
            acc1 += r1 ? m   : 0.f;
        }
    }
    // ---- dense ----
    {
        const int c   = (t > 12) ? 12 : t;
        const bool ok = (t < 13);
        #pragma unroll
        for (int j = 0; j < 2; ++j) {
            const int s   = 2 * c + j;
            const bool r1 = (s >= N_DENSE);
            const int d   = r1 ? (s - N_DENSE) : s;
            const float m = ok ? dx[j] * dense_w[d] : 0.f;
            acc0 += r1 ? 0.f : m;
            acc1 += r1 ? m   : 0.f;
        }
    }

    // ---- reduce across 16 lanes; one float2 store per pair ----
    #pragma unroll
    for (int o = 1; o < 16; o <<= 1) {
        acc0 += __shfl_xor(acc0, o);
        acc1 += __shfl_xor(acc1, o);
    }
    if (t == 0) {
        v2f r = { acc0, acc1 };
        __builtin_nontemporal_store(r, (v2f*)out + g);
    }
}

extern "C" void kernel_launch(void* const* d_in, const int* in_sizes, int n_in,
                              void* d_out, int out_size, void* d_ws, size_t ws_size,
                              hipStream_t stream) {
    const int*   sparse_ids    = (const int*)d_in[0];
    const int*   varlen_ids    = (const int*)d_in[1];
    const float* dense_x       = (const float*)d_in[2];
    const float* sparse_tables = (const float*)d_in[3];
    const float* varlen_tables = (const float*)d_in[4];
    const float* dense_w       = (const float*)d_in[5];
    float*       out           = (float*)d_out;
    unsigned int* vt16         = (unsigned int*)d_ws;   // 600000 B of scratch

    const int nconv = (N_VARLEN * VOCAB) / 2;           // 150000 u32
    convert_kernel<<<(nconv + 511) / 512, 512, 0, stream>>>(varlen_tables, vt16);

    logit_kernel<<<(B / 2) / 64, 1024, 0, stream>>>(    // 512 blocks x 1024 thr
        sparse_ids, varlen_ids, dense_x, sparse_tables, dense_w, vt16, out);
}